// Round 6
// baseline (224.116 us; speedup 1.0000x reference)
//
#include <hip/hip_runtime.h>
#include <hip/hip_fp16.h>

static constexpr int HH = 2048;
static constexpr int WW = 2048;
static constexpr int PADT = 24;   // top/bottom pad rows
static constexpr int PADL = 8;    // left/right pad cols
static constexpr int SW   = WW + 2 * PADL;          // 2064
static constexpr int PROWS = HH + 2 * PADT;         // 2096
static constexpr size_t PadElems = (size_t)PROWS * SW;
static constexpr int ROWS = 16;   // output rows per thread in filter kernels

// segment tables for +10 deg: lval(d)=round(d*tan(10deg)), runs of constant offset
__device__ constexpr int CS[9] = {-24,-19,-14,-8,-2, 3, 9,15,20};
__device__ constexpr int CE[9] = {-20,-15, -9,-3, 2, 8,14,19,24};
__device__ constexpr int CO[9] = { -4, -3, -2,-1, 0, 1, 2, 3, 4};

// ---- one slanted segment: vertical run [SS,EE] at col offset OO ----
template<int SS, int EE, int OO>
__device__ __forceinline__ void seg_one(const __half* __restrict__ tp, int h0, int w,
                                        float* __restrict__ acc) {
  constexpr int L = EE - SS + 1;        // 5 or 6
  const __half* p = tp + (h0 + SS + PADT) * SW + (w + OO + PADL);
  float ring[L - 1];
  float s = 0.0f;
#pragma unroll
  for (int k = 0; k < L - 1; ++k) { float v = __half2float(p[k * SW]); ring[k] = v; s += v; }
#pragma unroll
  for (int r = 0; r < ROWS; ++r) {
    float v = __half2float(p[(L - 1 + r) * SW]);
    acc[r] += s + v;
    s += v - ring[r % (L - 1)];
    ring[r % (L - 1)] = v;
  }
}

template<int SGN>   // +1 => +10deg, -1 => -10deg
__device__ __forceinline__ void filt_slant(const __half* __restrict__ tp, int h0, int w,
                                           float* __restrict__ acc) {
  seg_one<-24, -20, -4 * SGN>(tp, h0, w, acc);
  seg_one<-19, -15, -3 * SGN>(tp, h0, w, acc);
  seg_one<-14,  -9, -2 * SGN>(tp, h0, w, acc);
  seg_one< -8,  -3, -1 * SGN>(tp, h0, w, acc);
  seg_one< -2,   2,  0      >(tp, h0, w, acc);
  seg_one<  3,   8,  1 * SGN>(tp, h0, w, acc);
  seg_one<  9,  14,  2 * SGN>(tp, h0, w, acc);
  seg_one< 15,  19,  3 * SGN>(tp, h0, w, acc);
  seg_one< 20,  24,  4 * SGN>(tp, h0, w, acc);
}

// A: 0 => -10deg, 1 => 0deg, 2 => +10deg
template<int A>
__device__ __forceinline__ void filtN(const __half* __restrict__ tp, int h0, int w,
                                      float* __restrict__ acc) {
#pragma unroll
  for (int r = 0; r < ROWS; ++r) acc[r] = 0.0f;
  if constexpr (A == 1) {
    const __half* p = tp + (h0 - 24 + PADT) * SW + (w + PADL);
    float s = 0.0f;
#pragma unroll
    for (int k = 0; k < 48; ++k) s += __half2float(p[k * SW]);
#pragma unroll
    for (int r = 0; r < ROWS; ++r) {
      float vin = __half2float(p[(48 + r) * SW]);
      acc[r] = s + vin;
      s += vin - __half2float(p[r * SW]);
    }
  } else if constexpr (A == 0) {
    filt_slant<-1>(tp, h0, w, acc);
  } else {
    filt_slant<+1>(tp, h0, w, acc);
  }
}

// analytic 1/N (N = in-bounds tap count of zero-padded conv)
template<int A>
__device__ __forceinline__ float rcpcnt(int h, int w) {
  if (h >= 24 && h <= 2023 && w >= 4 && w <= 2043) return 1.0f / 49.0f;
  int cnt = 0;
  if constexpr (A == 1) {
    cnt = min(h + 24, HH - 1) - max(h - 24, 0) + 1;
  } else {
    const int sgn = (A == 0) ? -1 : 1;
#pragma unroll
    for (int j = 0; j < 9; ++j) {
      const int ww = w + sgn * CO[j];
      const int ov = min(h + CE[j], HH - 1) - max(h + CS[j], 0) + 1;
      if (ww >= 0 && ww < WW && ov > 0) cnt += ov;
    }
  }
  return 1.0f / (float)cnt;
}

// ---- pass A: bp = filt(tcur)/N ----
template<int A>
__global__ __launch_bounds__(256) void passA(const __half* __restrict__ tcur,
                                             __half* __restrict__ bp) {
  const int w  = blockIdx.x * 256 + threadIdx.x;
  const int h0 = blockIdx.y * ROWS;
  float acc[ROWS];
  filtN<A>(tcur, h0, w, acc);
#pragma unroll
  for (int r = 0; r < ROWS; ++r) {
    const int h = h0 + r;
    bp[(h + PADT) * SW + (w + PADL)] = __float2half(acc[r] * rcpcnt<A>(h, w));
  }
}

// ---- pass B (mid): tcur[i] -= filt(bp)/N  (in-place; own-pixel read/write only) ----
template<int A>
__global__ __launch_bounds__(256) void passB(const __half* __restrict__ bp,
                                             __half* __restrict__ tcur) {
  const int w  = blockIdx.x * 256 + threadIdx.x;
  const int h0 = blockIdx.y * ROWS;
  float acc[ROWS];
  filtN<A>(bp, h0, w, acc);
#pragma unroll
  for (int r = 0; r < ROWS; ++r) {
    const int h = h0 + r;
    const size_t ip = (size_t)(h + PADT) * SW + (w + PADL);
    tcur[ip] = __float2half(__half2float(tcur[ip]) - acc[r] * rcpcnt<A>(h, w));
  }
}

// ---- pass B (final): D = t0 - (tcur - filt(bp)/N), quantized int8 with per-(2row x 32col) scale.
// Qs[s*WW+w] packs rows (2s, 2s+1); scf[s*64 + w/32] is the dequant scale. ----
template<int A>
__global__ __launch_bounds__(256) void passBF(const __half* __restrict__ bp,
                                              const __half* __restrict__ tcur,
                                              const __half* __restrict__ t0h,
                                              short* __restrict__ Qs,
                                              float* __restrict__ scf) {
  const int w  = blockIdx.x * 256 + threadIdx.x;
  const int h0 = blockIdx.y * ROWS;
  float acc[ROWS];
  filtN<A>(bp, h0, w, acc);
#pragma unroll
  for (int r2 = 0; r2 < ROWS / 2; ++r2) {
    const int ha = h0 + 2 * r2, hb = ha + 1;
    const size_t ia = (size_t)ha * WW + w, ib = (size_t)hb * WW + w;
    const size_t pa = (size_t)(ha + PADT) * SW + (w + PADL);
    const size_t pb = (size_t)(hb + PADT) * SW + (w + PADL);
    const float res0 = __half2float(t0h[ia]) - __half2float(tcur[pa]) +
                       acc[2 * r2] * rcpcnt<A>(ha, w);
    const float res1 = __half2float(t0h[ib]) - __half2float(tcur[pb]) +
                       acc[2 * r2 + 1] * rcpcnt<A>(hb, w);
    float m = fmaxf(fabsf(res0), fabsf(res1));
#pragma unroll
    for (int off = 16; off >= 1; off >>= 1) m = fmaxf(m, __shfl_xor(m, off));
    const float scale = m * (1.0f / 127.0f);
    const float inv = (m > 0.0f) ? 127.0f / m : 0.0f;
    int q0 = (int)rintf(res0 * inv); q0 = min(max(q0, -127), 127);
    int q1 = (int)rintf(res1 * inv); q1 = min(max(q1, -127), 127);
    const int s = (h0 >> 1) + r2;
    Qs[(size_t)s * WW + w] = (short)((q0 & 0xff) | (q1 << 8));
    if ((threadIdx.x & 31) == 0) scf[s * 64 + (w >> 5)] = scale;
  }
}

// zero the pad frame of both fp16 staging buffers
__global__ __launch_bounds__(64) void zeropad(__half* __restrict__ tp, __half* __restrict__ bp) {
  __half* buf = blockIdx.y ? bp : tp;
  const int row = blockIdx.x;
  __half* r = buf + (size_t)row * SW;
  const __half z = __float2half(0.0f);
  if (row < PADT || row >= PADT + HH) {
    for (int c = threadIdx.x; c < SW; c += 64) r[c] = z;
  } else if (threadIdx.x < PADL) {
    r[threadIdx.x] = z;
    r[PADL + WW + threadIdx.x] = z;
  }
}

// tcur interior = t0h = y - X
__global__ __launch_bounds__(256) void sub2pad(const float* __restrict__ y,
                                               const float* __restrict__ X,
                                               __half* __restrict__ tcur,
                                               __half* __restrict__ t0h) {
  const int i = blockIdx.x * 256 + threadIdx.x;
  const int h = i >> 11, w = i & (WW - 1);
  const __half d = __float2half(y[i] - X[i]);
  tcur[(h + PADT) * SW + (w + PADL)] = d;
  t0h[i] = d;
}

__device__ __forceinline__ float reflectf(float x, int size) {
  const float span = (float)(size - 1);
  const float ax = fabsf(x);
  const float extra = fmodf(ax, span);
  const float flips = floorf(ax / span);
  float r = (fmodf(flips, 2.0f) == 0.0f) ? extra : (span - extra);
  return fminf(fmaxf(r, 0.0f), span);
}

__global__ __launch_bounds__(256) void gather_k(const short* __restrict__ Qs,
                                                const float* __restrict__ scf,
                                                const unsigned long long* __restrict__ coorU,
                                                const float* __restrict__ hX,
                                                float* __restrict__ out) {
  const int i = blockIdx.x * 256 + threadIdx.x;
  const unsigned long long cu = __builtin_nontemporal_load(&coorU[i]);
  union { unsigned long long u; float f[2]; } cc; cc.u = cu;
  const float gx = reflectf((cc.f[0] + 1.0f) * 0.5f * (float)(WW - 1), WW);
  const float gy = reflectf((cc.f[1] + 1.0f) * 0.5f * (float)(HH - 1), HH);
  const float x0 = floorf(gx), y0 = floorf(gy);
  const float wx = gx - x0, wy = gy - y0;
  const int xi0 = min(max((int)x0, 0), WW - 1);
  const int xi1 = min(max((int)(x0 + 1.0f), 0), WW - 1);
  const int yi0 = min(max((int)y0, 0), HH - 1);
  const int yi1 = min(max((int)(y0 + 1.0f), 0), HH - 1);
  const int s0 = yi0 >> 1, s1 = yi1 >> 1;
  const short qa0 = Qs[(size_t)s0 * WW + xi0];
  const short qa1 = Qs[(size_t)s0 * WW + xi1];
  const short qb0 = Qs[(size_t)s1 * WW + xi0];
  const short qb1 = Qs[(size_t)s1 * WW + xi1];
  const float sa0 = scf[s0 * 64 + (xi0 >> 5)];
  const float sa1 = scf[s0 * 64 + (xi1 >> 5)];
  const float sb0 = scf[s1 * 64 + (xi0 >> 5)];
  const float sb1 = scf[s1 * 64 + (xi1 >> 5)];
  const int r0sel = yi0 & 1, r1sel = yi1 & 1;
  const float v00 = (float)(r0sel ? (signed char)(qa0 >> 8) : (signed char)qa0) * sa0;
  const float v01 = (float)(r0sel ? (signed char)(qa1 >> 8) : (signed char)qa1) * sa1;
  const float v10 = (float)(r1sel ? (signed char)(qb0 >> 8) : (signed char)qb0) * sb0;
  const float v11 = (float)(r1sel ? (signed char)(qb1 >> 8) : (signed char)qb1) * sb1;
  const float hx = __builtin_nontemporal_load(&hX[i]);
  const float r = v00 * (1.0f - wx) * (1.0f - wy) + v01 * wx * (1.0f - wy) +
                  v10 * (1.0f - wx) * wy + v11 * wx * wy + hx;
  __builtin_nontemporal_store(r, &out[i]);
}

extern "C" void kernel_launch(void* const* d_in, const int* in_sizes, int n_in,
                              void* d_out, int out_size, void* d_ws, size_t ws_size,
                              hipStream_t stream) {
  const float* X    = (const float*)d_in[0];
  const float* y    = (const float*)d_in[1];
  const float* hX   = (const float*)d_in[2];
  const float* coor = (const float*)d_in[3];
  float* out = (float*)d_out;

  __half* tcur = (__half*)d_ws;             // padded t, fp16,  8.65 MB
  __half* bp   = tcur + PadElems;           // padded b, fp16,  8.65 MB
  __half* t0h  = bp + PadElems;             // t0 = y-X, fp16,  8.39 MB
  short*  Qs   = (short*)(t0h + (size_t)HH * WW);      // int8 row-pair D, 4.19 MB
  float*  scf  = (float*)(Qs + (size_t)(HH / 2) * WW); // scales, 256 KB

  const int n = HH * WW;
  dim3 fgrd(WW / 256, HH / ROWS, 1);

  zeropad<<<dim3(PROWS, 2, 1), 64, 0, stream>>>(tcur, bp);
  sub2pad<<<n / 256, 256, 0, stream>>>(y, X, tcur, t0h);

  // iteration 0: -10deg
  passA<0><<<fgrd, 256, 0, stream>>>(tcur, bp);
  passB<0><<<fgrd, 256, 0, stream>>>(bp, tcur);
  // iteration 1: 0deg
  passA<1><<<fgrd, 256, 0, stream>>>(tcur, bp);
  passB<1><<<fgrd, 256, 0, stream>>>(bp, tcur);
  // iteration 2: +10deg  (emit quantized D = t0 - t3)
  passA<2><<<fgrd, 256, 0, stream>>>(tcur, bp);
  passBF<2><<<fgrd, 256, 0, stream>>>(bp, tcur, t0h, Qs, scf);

  gather_k<<<n / 256, 256, 0, stream>>>(Qs, scf, (const unsigned long long*)coor, hX, out);
}